// Round 13
// baseline (902.178 us; speedup 1.0000x reference)
//
#include <hip/hip_runtime.h>
#include <math.h>

#define LL 24
#define DD 512
#define HH 16
#define FFD 2048
#define VV 1025
#define SS 2047
#define TKV 2048
#define TYY 1535
#define NBLK 256
#define NT 512

typedef float f4v __attribute__((ext_vector_type(4)));

// d_out layout (floats), concatenated in reference return order
constexpr size_t O_YNEW  = 0;                                  // 1537
constexpr size_t O_KOUT  = 1537;                               // 24*2048*512
constexpr size_t O_VOUT  = O_KOUT + (size_t)LL*TKV*DD;
constexpr size_t O_YEMB  = O_VOUT + (size_t)LL*TKV*DD;         // 1536*512
constexpr size_t O_LOGITS= O_YEMB + (size_t)(TYY+1)*DD;        // 1025
constexpr size_t O_SAMP  = O_LOGITS + VV;                      // 1

// ws: u32[0..4096) per-block flags (stride 16 u32 = 64B). float data at 4352:
constexpr int W_WYA = 0;      // 2 parities x 16 heads x 512 (atomic, unnorm. attn-out)
constexpr int W_DEN = 16384;  // 2 parities x 16 heads (stride 16)
constexpr int W_FFA = 16896;  // 2 parities x 8 copies x 512

struct P {
  const int* y; const float* k; const float* v; const float* yemb;
  const float* alpha; const float* emb;
  const float* ipw; const float* ipb; const float* ow; const float* ob;
  const float* l1w; const float* l1b; const float* l2w; const float* l2b;
  const float* f1w; const float* f1b; const float* f2w; const float* f2b;
  const float* pw; const float* pb; const float* noise;
  float* out; float* ws;
};

__device__ __forceinline__ float dot4(float4 a, float4 b){
  return a.x*b.x + a.y*b.y + a.z*b.z + a.w*b.w;
}
__device__ __forceinline__ float ldv(const float* pp){
  return __hip_atomic_load(pp, __ATOMIC_RELAXED, __HIP_MEMORY_SCOPE_AGENT);
}
__device__ __forceinline__ void stv(float* pp, float v){
  __hip_atomic_store(pp, v, __ATOMIC_RELAXED, __HIP_MEMORY_SCOPE_AGENT);
}
__device__ __forceinline__ unsigned ldu(const unsigned* pp){
  return __hip_atomic_load(pp, __ATOMIC_RELAXED, __HIP_MEMORY_SCOPE_AGENT);
}

// LDS-only block barrier: does NOT drain vmcnt (prefetch streams survive).
__device__ __forceinline__ void lbar(){
  asm volatile("s_waitcnt lgkmcnt(0)" ::: "memory");
  __builtin_amdgcn_s_barrier();
  __builtin_amdgcn_sched_barrier(0);
}
// arrive: per-wave full drain, HW barrier, t0 stores flag.
__device__ __forceinline__ void barr_arrive(unsigned* flags, unsigned ph){
  asm volatile("s_waitcnt vmcnt(0) lgkmcnt(0)" ::: "memory");
  __builtin_amdgcn_s_barrier();
  __builtin_amdgcn_sched_barrier(0);
  if (threadIdx.x == 0)
    __hip_atomic_store(&flags[blockIdx.x*16], ph, __ATOMIC_RELAXED, __HIP_MEMORY_SCOPE_AGENT);
}
// global wait: wave0 polls all 256 flags; other waves park at s_barrier.
__device__ __forceinline__ void barr_wait(unsigned* flags, unsigned ph){
  const int t = threadIdx.x;
  if (t < 64){
    for (;;){
      int ok = 1;
      #pragma unroll
      for (int i=0;i<4;++i) ok &= (int)(ldu(&flags[(t*4+i)*16]) >= ph);
      if (__all(ok)) break;
    }
  }
  __builtin_amdgcn_s_barrier();
  asm volatile("" ::: "memory");
}

__device__ __forceinline__ float2 bsum2(float a, float b2, float2* r8, int t){
  for (int off=32; off; off>>=1){ a += __shfl_xor(a, off); b2 += __shfl_xor(b2, off); }
  lbar();
  if ((t & 63) == 0) r8[t >> 6] = make_float2(a, b2);
  lbar();
  float2 s = r8[0];
  #pragma unroll
  for (int i=1;i<8;++i){ s.x += r8[i].x; s.y += r8[i].y; }
  return s;
}
__device__ __forceinline__ void ln512g(float r, float g, float bb,
                                       float* dst, float2* r8, int t)
{
  float2 s = bsum2(r, r*r, r8, t);
  float mean = s.x * (1.f/512.f);
  float var  = fmaxf(s.y * (1.f/512.f) - mean*mean, 0.f);
  dst[t] = (r - mean) * rsqrtf(var + 1e-5f) * g + bb;
}
__device__ __forceinline__ void bargmax(float v, int i, float* r8v, int* r8i,
                                        int t, float& ov, int& oi)
{
  for (int off=32; off; off>>=1){
    float v2 = __shfl_xor(v, off); int i2 = __shfl_xor(i, off);
    if (v2 > v || (v2 == v && i2 < i)){ v = v2; i = i2; }
  }
  lbar();
  if ((t & 63) == 0){ r8v[t>>6] = v; r8i[t>>6] = i; }
  lbar();
  ov = r8v[0]; oi = r8i[0];
  #pragma unroll
  for (int kk=1; kk<8; ++kk){
    float v2 = r8v[kk]; int i2 = r8i[kk];
    if (v2 > ov || (v2 == ov && i2 < oi)){ ov = v2; oi = i2; }
  }
}

// q rows for all blocks; +kn/vn rows for c==15 blocks (tail handling)
struct RegsQX { float4 w[24]; float b[12]; };
struct RegsKV { float4 k0,k1,v0,v1; };
struct RegsLN { float g2,b2,fb2; };
struct RegsW  { float4 w[8]; };            // ow column slab: row t, cols h*32..+32
struct RegsBC { float4 f1p0,f1p1,f2p0,f2p1; float g1,b1,obv,f1bv; };

__device__ __forceinline__ void issueQX(const P& p, int l, int h, int c, int t,
                                        RegsQX& q){
  const int lane = t & 63, w = t >> 6;
  const float* Wb = p.ipw + (size_t)l*1536*DD;
  const float* Bb = p.ipb + (size_t)l*1536;
  #pragma unroll
  for (int pp=0; pp<4; ++pp){
    int row = h*32 + w + 8*pp;
    const float4* wr = (const float4*)(Wb + (size_t)row*DD);
    q.w[2*pp] = wr[lane]; q.w[2*pp+1] = wr[lane+64];
    q.b[pp] = Bb[row];
  }
  if (c == 15){
    #pragma unroll
    for (int pp=4; pp<12; ++pp){
      int r = w + 8*((pp-4)&3);
      int row = ((pp < 8) ? 512 : 1024) + h*32 + r;
      const float4* wr = (const float4*)(Wb + (size_t)row*DD);
      q.w[2*pp] = wr[lane]; q.w[2*pp+1] = wr[lane+64];
      q.b[pp] = Bb[row];
    }
  }
}
__device__ __forceinline__ void issueL(const P& p, int b, int t, RegsQX& q){
  const int lane = t & 63, w = t >> 6;
  int row = (w < 4) ? b*4 + w : ((b == 255 && w == 4) ? 1024 : -1);
  if (row >= 0){
    const float4* wr = (const float4*)(p.pw + (size_t)row*DD);
    q.w[0] = wr[lane]; q.w[1] = wr[lane+64];
    q.b[0] = p.pb[row];
  }
}
__device__ __forceinline__ void issueKV(const P& p, int l, int h, int c, int t,
                                        RegsKV& kv){
  const float* kb = p.k + (size_t)l*SS*DD;
  const float* vb = p.v + (size_t)l*SS*DD;
  const int s0 = c*128;
  kv.k0 = kv.v0 = kv.k1 = kv.v1 = make_float4(0,0,0,0);
  {
    int row = t >> 3, c4 = (t & 7)*4, s = s0 + row;
    if (s < SS){
      kv.k0 = *(const float4*)&kb[(size_t)s*DD + h*32 + c4];
      kv.v0 = *(const float4*)&vb[(size_t)s*DD + h*32 + c4];
    }
  }
  {
    int idx = t + NT;
    int row = idx >> 3, c4 = (idx & 7)*4, s = s0 + row;
    if (s < SS){
      kv.k1 = *(const float4*)&kb[(size_t)s*DD + h*32 + c4];
      kv.v1 = *(const float4*)&vb[(size_t)s*DD + h*32 + c4];
    }
  }
}
__device__ __forceinline__ void issueLN(const P& p, int l, int t, RegsLN& r){
  r.g2 = p.l2w[(size_t)l*DD + t];
  r.b2 = p.l2b[(size_t)l*DD + t];
  r.fb2= p.f2b[(size_t)l*DD + t];
}
__device__ __forceinline__ void issueW(const P& p, int l, int h, int t, RegsW& wsl){
  const float4* wr = (const float4*)(p.ow + (size_t)l*DD*DD + (size_t)t*DD + h*32);
  #pragma unroll
  for (int i=0;i<8;++i) wsl.w[i] = wr[i];
}
__device__ __forceinline__ void issueBCsmall(const P& p, int l, int b, int t,
                                             RegsBC& bc){
  bc.f1bv = p.f1b[(size_t)l*FFD + b*8 + (t>>6)];
  bc.g1  = p.l1w[(size_t)l*DD + t];
  bc.b1  = p.l1b[(size_t)l*DD + t];
  bc.obv = p.ob[(size_t)l*DD + t];
}
__device__ __forceinline__ void issueF12(const P& p, int l, int b, int t,
                                         RegsBC& bc){
  const int lane = t & 63, w = t >> 6;
  {
    int f = b*8 + w;
    const float4* wr = (const float4*)(p.f1w + (size_t)l*FFD*DD + (size_t)f*DD);
    bc.f1p0 = wr[lane]; bc.f1p1 = wr[lane+64];
  }
  {
    const float* wr = p.f2w + (size_t)l*DD*FFD + (size_t)t*FFD + b*8;
    bc.f2p0 = *(const float4*)wr;
    bc.f2p1 = *(const float4*)(wr+4);
  }
}

__global__ __launch_bounds__(NT, 1) void mega_kernel(P p)
{
  __shared__ __align__(16) float S_kl[128*33];   // K tile / sampler overlay
  __shared__ __align__(16) float S_vl[128*33];   // V tile
  __shared__ __align__(16) float S_x[512];
  __shared__ float S_ps[128];
  __shared__ float S_cacc[512];
  __shared__ float S_q[32];
  __shared__ __align__(16) float S_num[32];
  __shared__ float S_rcp[16];
  __shared__ float S_scal[4];
  __shared__ float S_hdn[8];
  __shared__ float2 S_r82[8];
  __shared__ float S_r8v[8];
  __shared__ int   S_r8i[8];

  const int t = threadIdx.x, b = blockIdx.x;
  const int lane = t & 63, w = t >> 6;
  const int h = b & 15, c = b >> 4;
  unsigned* flags = (unsigned*)p.ws;
  float* wsd = p.ws + 4352;
  float* out = p.out;
  unsigned ph = 0;

  RegsQX qx; RegsKV kv; RegsLN lnp; RegsW wsl; RegsBC bc;
  issueQX(p, 0, h, c, t, qx);
  issueKV(p, 0, h, c, t, kv);

  for (int l = 0; l < LL; ++l){
    const int par = l & 1, np = (l+1) & 1;
    // ================= PH_A body =================
    float fs = 0.f;
    if (l > 0){
      const float* fb = wsd + W_FFA + (size_t)np*4096;
      #pragma unroll
      for (int i=0;i<8;++i) fs += ldv(&fb[i*512 + t]);
    }
    issueW(p, l, h, t, wsl);               // ow column slab (L2-dedup per XCD)
    issueBCsmall(p, l, b, t, bc);

    if (l == 0){
      int tok = p.y[1535];
      float a0 = p.alpha[0];
      float ev = p.emb[(size_t)tok*DD + t];
      float ang = 1535.0f * expf((float)(2*(t>>1)) * (-9.210340371976184f/512.0f));
      float pe = (t & 1) ? cosf(ang) : sinf(ang);
      S_x[t] = ev + a0*pe;
      if (b == 0) for (int i=t;i<1536;i+=NT)
        __builtin_nontemporal_store((float)p.y[i], out + O_YNEW + i);
      if (b == 1)
        __builtin_nontemporal_store(ev, out + O_YEMB + (size_t)TYY*DD + t);
      lbar();
    } else {
      float r = S_x[t] + lnp.fb2 + fs;
      ln512g(r, lnp.g2, lnp.b2, S_x, S_r82, t);
      lbar();
    }

    // q GEMV (+ kn/vn rows for c==15 → LDS row 127 + tail store)
    #pragma unroll
    for (int pp=0; pp<4; ++pp){
      float s = dot4(qx.w[2*pp],   ((const float4*)S_x)[lane])
              + dot4(qx.w[2*pp+1], ((const float4*)S_x)[lane+64]);
      for (int off=32; off; off>>=1) s += __shfl_xor(s, off);
      if (lane == 0) S_q[w + 8*pp] = s + qx.b[pp];
    }
    if (c == 15){
      #pragma unroll
      for (int pp=4; pp<12; ++pp){
        float s = dot4(qx.w[2*pp],   ((const float4*)S_x)[lane])
                + dot4(qx.w[2*pp+1], ((const float4*)S_x)[lane+64]);
        for (int off=32; off; off>>=1) s += __shfl_xor(s, off);
        if (lane == 0){
          int r = w + 8*((pp-4)&3);
          float val = s + qx.b[pp];
          if (pp < 8) S_kl[127*33 + r] = val;
          else        S_vl[127*33 + r] = val;
          __builtin_nontemporal_store(val,
            out + ((pp<8) ? O_KOUT : O_VOUT) + (size_t)l*TKV*DD + (size_t)SS*DD + h*32 + r);
        }
      }
    }
    // KV regs -> LDS tile (row s>=SS skipped; c15 row127 = kn/vn)
    {
      int r0 = t >> 3, c40 = (t & 7)*4, s0c = c*128;
      if (s0c + r0 < SS){
        int lb = r0*33 + c40;
        S_kl[lb+0]=kv.k0.x; S_kl[lb+1]=kv.k0.y; S_kl[lb+2]=kv.k0.z; S_kl[lb+3]=kv.k0.w;
        S_vl[lb+0]=kv.v0.x; S_vl[lb+1]=kv.v0.y; S_vl[lb+2]=kv.v0.z; S_vl[lb+3]=kv.v0.w;
      }
      int idx = t + NT;
      int r1 = idx >> 3, c41 = (idx & 7)*4;
      if (s0c + r1 < SS){
        int lb1 = r1*33 + c41;
        S_kl[lb1+0]=kv.k1.x; S_kl[lb1+1]=kv.k1.y; S_kl[lb1+2]=kv.k1.z; S_kl[lb1+3]=kv.k1.w;
        S_vl[lb1+0]=kv.v1.x; S_vl[lb1+1]=kv.v1.y; S_vl[lb1+2]=kv.v1.z; S_vl[lb1+3]=kv.v1.w;
      }
    }
    lbar();

    // scores (max-free, no mask: tail lives in chunk 15 row 127) + PV partial
    {
      float pv = 0.f;
      if (t < 128){
        float acc = 0.f;
        #pragma unroll
        for (int j=0;j<32;++j) acc += S_kl[t*33+j]*S_q[j];
        pv = expf(acc * 0.17677669529663687f);
      }
      if (t < 128) S_ps[t] = pv;
      lbar();
      int g = t >> 5, j = t & 31;
      float ca = 0.f;
      #pragma unroll
      for (int i=0;i<8;++i){ int r = g*8+i; ca += S_ps[r]*S_vl[r*33+j]; }
      S_cacc[g*32 + j] = ca;
      lbar();
      if (t < 32){                      // wave0: num[32] -> LDS
        float v2 = 0.f;
        #pragma unroll
        for (int gg=0; gg<16; ++gg) v2 += S_cacc[gg*32 + t];
        S_num[t] = v2;
      } else if (t >= 64 && t < 128){   // wave1: den -> atomic
        int ll2 = t - 64;
        float dv = S_ps[ll2] + S_ps[ll2+64];
        for (int off=32; off; off>>=1) dv += __shfl_xor(dv, off);
        if (ll2 == 0) atomicAdd(&wsd[W_DEN + par*256 + h*16], dv);
      }
      lbar();
      // unnormalized out-proj: yc(t) = W_h[t,:] @ num  -> atomic into WYA
      float yc = 0.f;
      #pragma unroll
      for (int i=0;i<8;++i) yc += dot4(wsl.w[i], ((const float4*)S_num)[i]);
      atomicAdd(&wsd[W_WYA + par*8192 + h*512 + t], yc);
    }
    barr_arrive(flags, ++ph);
    // ---- post-1 window: KV cache copy (nt) + f1w/f2w + LN2 params ----
    {
      const int s0 = c*128;
      float* ko = out + O_KOUT + (size_t)l*TKV*DD;
      float* vo = out + O_VOUT + (size_t)l*TKV*DD;
      {
        int row = t >> 3, c4 = (t & 7)*4, s = s0 + row;
        if (s < SS){
          size_t go = (size_t)s*DD + h*32 + c4;
          __builtin_nontemporal_store(kv.k0.x, ko+go);
          __builtin_nontemporal_store(kv.k0.y, ko+go+1);
          __builtin_nontemporal_store(kv.k0.z, ko+go+2);
          __builtin_nontemporal_store(kv.k0.w, ko+go+3);
          __builtin_nontemporal_store(kv.v0.x, vo+go);
          __builtin_nontemporal_store(kv.v0.y, vo+go+1);
          __builtin_nontemporal_store(kv.v0.z, vo+go+2);
          __builtin_nontemporal_store(kv.v0.w, vo+go+3);
        }
      }
      {
        int idx = t + NT;
        int row = idx >> 3, c4 = (idx & 7)*4, s = s0 + row;
        if (s < SS){
          size_t go = (size_t)s*DD + h*32 + c4;
          __builtin_nontemporal_store(kv.k1.x, ko+go);
          __builtin_nontemporal_store(kv.k1.y, ko+go+1);
          __builtin_nontemporal_store(kv.k1.z, ko+go+2);
          __builtin_nontemporal_store(kv.k1.w, ko+go+3);
          __builtin_nontemporal_store(kv.v1.x, vo+go);
          __builtin_nontemporal_store(kv.v1.y, vo+go+1);
          __builtin_nontemporal_store(kv.v1.z, vo+go+2);
          __builtin_nontemporal_store(kv.v1.w, vo+go+3);
        }
      }
    }
    issueF12(p, l, b, t, bc);
    issueLN(p, l, t, lnp);
    barr_wait(flags, ph);

    // ================= PH_C body =================
    {
      float wv[16];
      #pragma unroll
      for (int hh=0; hh<16; ++hh)
        wv[hh] = ldv(&wsd[W_WYA + par*8192 + hh*512 + t]);
      if (t < 16) S_rcp[t] = 1.f / ldv(&wsd[W_DEN + par*256 + t*16]);
      lbar();
      float xs = 0.f;
      #pragma unroll
      for (int hh=0; hh<16; ++hh) xs += wv[hh] * S_rcp[hh];
      float r = S_x[t] + bc.obv + xs;
      ln512g(r, bc.g1, bc.b1, S_x, S_r82, t);
      lbar();
      {
        float s = dot4(bc.f1p0, ((const float4*)S_x)[lane])
                + dot4(bc.f1p1, ((const float4*)S_x)[lane+64]);
        for (int off=32; off; off>>=1) s += __shfl_xor(s, off);
        if (lane == 0) S_hdn[w] = fmaxf(s + bc.f1bv, 0.f);
      }
      lbar();
      float con = bc.f2p0.x*S_hdn[0]+bc.f2p0.y*S_hdn[1]
                + bc.f2p0.z*S_hdn[2]+bc.f2p0.w*S_hdn[3]
                + bc.f2p1.x*S_hdn[4]+bc.f2p1.y*S_hdn[5]
                + bc.f2p1.z*S_hdn[6]+bc.f2p1.w*S_hdn[7];
      atomicAdd(&wsd[W_FFA + (size_t)par*4096 + (size_t)(b&7)*512 + t], con);
      // zero next-parity buffers (WYA/DEN/FFA) for layer l+1
      if (t < 16) stv(&wsd[W_FFA + (size_t)np*4096 + b*16 + t], 0.f);
      if (t < 32) stv(&wsd[W_WYA + (size_t)np*8192 + b*32 + t], 0.f);
      if (b < 16 && t == 0) stv(&wsd[W_DEN + np*256 + b*16], 0.f);
    }
    barr_arrive(flags, ++ph);
    // ---- post-2 window: next layer q(+kn/vn) weights + KV tile ----
    if (l < 23){
      issueQX(p, l+1, h, c, t, qx);
      issueKV(p, l+1, h, c, t, kv);
    } else {
      issueL(p, b, t, qx);
    }
    barr_wait(flags, ph);
  }

  // ================= LOGITS =================
  {
    float fs = 0.f;
    const float* fb = wsd + W_FFA + (size_t)((LL-1)&1)*4096;
    #pragma unroll
    for (int i=0;i<8;++i) fs += ldv(&fb[i*512 + t]);
    float r = S_x[t] + lnp.fb2 + fs;
    ln512g(r, lnp.g2, lnp.b2, S_x, S_r82, t);
    lbar();
    if (w < 4 || (b == 255 && w == 4)){
      int row = (w < 4) ? b*4 + w : 1024;
      float s = dot4(qx.w[0], ((const float4*)S_x)[lane])
              + dot4(qx.w[1], ((const float4*)S_x)[lane+64]);
      for (int off=32; off; off>>=1) s += __shfl_xor(s, off);
      if (lane == 0) stv(&out[O_LOGITS+row], s + qx.b[0]);
    }
  }
  barr_arrive(flags, ++ph);
  barr_wait(flags, ph);

  // ========= SAMPLER (block 0) / yemb copy (blocks 1..255) =========
  if (b == 0){
    float* lg  = S_kl;
    float* lgc = S_kl + 1025;
    int*   pen = (int*)(S_kl + 2050);
    for (int i=t;i<VV;i+=NT){ lg[i] = ldv(&out[O_LOGITS+i]); pen[i]=0; }
    lbar();
    for (int i=t;i<1536;i+=NT) pen[p.y[i]] = 1;
    lbar();
    for (int i=t;i<VV;i+=NT){
      if (pen[i]){ float s = lg[i]; lg[i] = (s<0.f) ? s*1.35f : s/1.35f; }
    }
    lbar();
    for (int i=t;i<VV;i+=NT) lgc[i]=lg[i];
    lbar();
    float sM = 0.f, sPiv = 0.f;
    for (int it=0; it<15; ++it){
      float bv = -INFINITY; int bi = VV;
      for (int i=t;i<VV;i+=NT){ float v2=lgc[i]; if (v2>bv){bv=v2;bi=i;} }
      float ov; int oi;
      bargmax(bv, bi, S_r8v, S_r8i, t, ov, oi);
      if (it==0)  sM   = ov;
      if (it==14) sPiv = ov;
      if (t==0) lgc[oi] = -INFINITY;
      lbar();
    }
    float zl = 0.f;
    for (int i=t;i<VV;i+=NT){
      float lv = lg[i];
      float pv2 = (lv < sPiv) ? 0.f : expf(lv - sM);
      lgc[i] = pv2; zl += pv2;
    }
    {
      float2 s = bsum2(zl, 0.f, S_r82, t);
      zl = s.x;
    }
    lbar();
    float bv=-INFINITY; int bi=VV;
    for (int i=t;i<VV;i+=NT){
      float val = (lgc[i]/zl)/p.noise[i];
      if (val>bv){bv=val;bi=i;}
    }
    float ov; int oi;
    bargmax(bv, bi, S_r8v, S_r8i, t, ov, oi);
    if (t==0){
      float sf = (float)oi;
      out[O_SAMP] = sf;
      out[O_YNEW+1536] = sf;
    }
  } else {
    // yemb copy: aligned f4 stores composed from two aligned f4 loads.
    const int nf4 = (TYY*DD - 4)/4;   // 196607
    for (int qq = (b-1)*NT + t; qq < nf4; qq += 255*NT){
      float4 a = *(const float4*)&p.yemb[qq*4];
      float4 bq = *(const float4*)&p.yemb[qq*4 + 4];
      f4v o = {a.w, bq.x, bq.y, bq.z};
      __builtin_nontemporal_store(o, (f4v*)(out + O_YEMB + 3 + (size_t)qq*4));
    }
    if (b == 1){
      if (t < 3) __builtin_nontemporal_store(p.yemb[t], out + O_YEMB + t);
      if (t == 3) __builtin_nontemporal_store(p.yemb[TYY*DD-1], out + O_YEMB + TYY*DD - 1);
    }
  }
}

extern "C" void kernel_launch(void* const* d_in, const int* in_sizes, int n_in,
                              void* d_out, int out_size, void* d_ws, size_t ws_size,
                              hipStream_t stream)
{
  P p;
  p.y    = (const int*)d_in[0];
  p.k    = (const float*)d_in[1];
  p.v    = (const float*)d_in[2];
  p.yemb = (const float*)d_in[3];
  p.alpha= (const float*)d_in[5];
  p.emb  = (const float*)d_in[6];
  p.ipw  = (const float*)d_in[7];
  p.ipb  = (const float*)d_in[8];
  p.ow   = (const float*)d_in[9];
  p.ob   = (const float*)d_in[10];
  p.l1w  = (const float*)d_in[11];
  p.l1b  = (const float*)d_in[12];
  p.l2w  = (const float*)d_in[13];
  p.l2b  = (const float*)d_in[14];
  p.f1w  = (const float*)d_in[15];
  p.f1b  = (const float*)d_in[16];
  p.f2w  = (const float*)d_in[17];
  p.f2b  = (const float*)d_in[18];
  p.pw   = (const float*)d_in[19];
  p.pb   = (const float*)d_in[20];
  p.noise= (const float*)d_in[21];
  p.out  = (float*)d_out;
  p.ws   = (float*)d_ws;

  // zero flags (17408 B) + WYA/DEN/FFA (both parities): (4352+25088)*4 B
  hipMemsetAsync(d_ws, 0, 117760, stream);
  void* args[] = { &p };
  hipLaunchCooperativeKernel((void*)mega_kernel, dim3(NBLK), dim3(NT), args, 0, stream);
}

// Round 14
// 442.717 us; speedup vs baseline: 2.0378x; 2.0378x over previous
//
#include <hip/hip_runtime.h>
#include <math.h>

#define LL 24
#define DD 512
#define HH 16
#define FFD 2048
#define VV 1025
#define SS 2047
#define TKV 2048
#define TYY 1535
#define NBLK 256
#define NT 512

typedef float f4v __attribute__((ext_vector_type(4)));

// d_out layout (floats), concatenated in reference return order
constexpr size_t O_YNEW  = 0;                                  // 1537
constexpr size_t O_KOUT  = 1537;                               // 24*2048*512
constexpr size_t O_VOUT  = O_KOUT + (size_t)LL*TKV*DD;
constexpr size_t O_YEMB  = O_VOUT + (size_t)LL*TKV*DD;         // 1536*512
constexpr size_t O_LOGITS= O_YEMB + (size_t)(TYY+1)*DD;        // 1025
constexpr size_t O_SAMP  = O_LOGITS + VV;                      // 1

// ws: u32[0..4096) per-block flags (stride 16 u32 = 64B). float data at 4352:
constexpr int W_X1A = 0;      // 2 parities x 4 copies x 512 (atomic out-proj)
constexpr int W_FFA = 4096;   // 2 parities x 8 copies x 512 (atomic FFN2)
constexpr int W_NUM = 12288;  // 2 parities x 16 heads x 32 (atomic flash num)
constexpr int W_DEN = 13312;  // 2 parities x 16 heads (stride 16)
constexpr int W_KN  = 13824;  // 512 k_new
constexpr int W_VN  = 14336;  // 512 v_new

struct P {
  const int* y; const float* k; const float* v; const float* yemb;
  const float* alpha; const float* emb;
  const float* ipw; const float* ipb; const float* ow; const float* ob;
  const float* l1w; const float* l1b; const float* l2w; const float* l2b;
  const float* f1w; const float* f1b; const float* f2w; const float* f2b;
  const float* pw; const float* pb; const float* noise;
  float* out; float* ws;
};

__device__ __forceinline__ float dot4(float4 a, float4 b){
  return a.x*b.x + a.y*b.y + a.z*b.z + a.w*b.w;
}
__device__ __forceinline__ float ldv(const float* pp){
  return __hip_atomic_load(pp, __ATOMIC_RELAXED, __HIP_MEMORY_SCOPE_AGENT);
}
__device__ __forceinline__ void stv(float* pp, float v){
  __hip_atomic_store(pp, v, __ATOMIC_RELAXED, __HIP_MEMORY_SCOPE_AGENT);
}
__device__ __forceinline__ unsigned ldu(const unsigned* pp){
  return __hip_atomic_load(pp, __ATOMIC_RELAXED, __HIP_MEMORY_SCOPE_AGENT);
}

// LDS-only block barrier: does NOT drain vmcnt (prefetch streams survive).
__device__ __forceinline__ void lbar(){
  asm volatile("s_waitcnt lgkmcnt(0)" ::: "memory");
  __builtin_amdgcn_s_barrier();
  __builtin_amdgcn_sched_barrier(0);
}
// arrive: per-wave full drain (critical stores + atomics), HW barrier, t0 flags.
__device__ __forceinline__ void barr_arrive(unsigned* flags, unsigned ph){
  asm volatile("s_waitcnt vmcnt(0) lgkmcnt(0)" ::: "memory");
  __builtin_amdgcn_s_barrier();
  __builtin_amdgcn_sched_barrier(0);
  if (threadIdx.x == 0)
    __hip_atomic_store(&flags[blockIdx.x*16], ph, __ATOMIC_RELAXED, __HIP_MEMORY_SCOPE_AGENT);
}
// global wait: wave0 polls all 256 flags; other waves park at s_barrier.
__device__ __forceinline__ void barr_wait(unsigned* flags, unsigned ph){
  const int t = threadIdx.x;
  if (t < 64){
    for (;;){
      int ok = 1;
      #pragma unroll
      for (int i=0;i<4;++i) ok &= (int)(ldu(&flags[(t*4+i)*16]) >= ph);
      if (__all(ok)) break;
    }
  }
  __builtin_amdgcn_s_barrier();
  asm volatile("" ::: "memory");
}
// intra-head wait: poll only head h's 16 flags (blocks cc*16+h).
__device__ __forceinline__ void barr_wait_head(unsigned* flags, unsigned ph, int h){
  const int t = threadIdx.x;
  if (t < 64){
    for (;;){
      int ok = 1;
      if (t < 16) ok = (int)(ldu(&flags[(t*16 + h)*16]) >= ph);
      if (__all(ok)) break;
    }
  }
  __builtin_amdgcn_s_barrier();
  asm volatile("" ::: "memory");
}

__device__ __forceinline__ float2 bsum2(float a, float b2, float2* r8, int t){
  for (int off=32; off; off>>=1){ a += __shfl_xor(a, off); b2 += __shfl_xor(b2, off); }
  lbar();
  if ((t & 63) == 0) r8[t >> 6] = make_float2(a, b2);
  lbar();
  float2 s = r8[0];
  #pragma unroll
  for (int i=1;i<8;++i){ s.x += r8[i].x; s.y += r8[i].y; }
  return s;
}
__device__ __forceinline__ void ln512g(float r, float g, float bb,
                                       float* dst, float2* r8, int t)
{
  float2 s = bsum2(r, r*r, r8, t);
  float mean = s.x * (1.f/512.f);
  float var  = fmaxf(s.y * (1.f/512.f) - mean*mean, 0.f);
  dst[t] = (r - mean) * rsqrtf(var + 1e-5f) * g + bb;
}
__device__ __forceinline__ void bargmax(float v, int i, float* r8v, int* r8i,
                                        int t, float& ov, int& oi)
{
  for (int off=32; off; off>>=1){
    float v2 = __shfl_xor(v, off); int i2 = __shfl_xor(i, off);
    if (v2 > v || (v2 == v && i2 < i)){ v = v2; i = i2; }
  }
  lbar();
  if ((t & 63) == 0){ r8v[t>>6] = v; r8i[t>>6] = i; }
  lbar();
  ov = r8v[0]; oi = r8i[0];
  #pragma unroll
  for (int kk=1; kk<8; ++kk){
    float v2 = r8v[kk]; int i2 = r8i[kk];
    if (v2 > ov || (v2 == ov && i2 < oi)){ ov = v2; oi = i2; }
  }
}

struct RegsQ  { float4 w[8]; float b[4]; };
struct RegsKV { float4 k0,k1,v0,v1; };
struct RegsTl { float4 t0,t1; float bias; };
struct RegsLN { float g2,b2,fb2; };
struct RegsBC { float2 oww; float4 f1p0,f1p1,f2p0,f2p1;
                float g1,b1,obv,f1bv; };

__device__ __forceinline__ void issueQ(const P& p, int l, int h, int t, RegsQ& q){
  const int lane = t & 63, w = t >> 6;
  const float* Wb = p.ipw + (size_t)l*1536*DD;
  const float* Bb = p.ipb + (size_t)l*1536;
  #pragma unroll
  for (int pp=0; pp<4; ++pp){
    int row = h*32 + w + 8*pp;
    const float4* wr = (const float4*)(Wb + (size_t)row*DD);
    q.w[2*pp] = wr[lane]; q.w[2*pp+1] = wr[lane+64];
    q.b[pp] = Bb[row];
  }
}
__device__ __forceinline__ void issueL(const P& p, int b, int t, RegsQ& q){
  const int lane = t & 63, w = t >> 6;
  int row = (w < 4) ? b*4 + w : ((b == 255 && w == 4) ? 1024 : -1);
  if (row >= 0){
    const float4* wr = (const float4*)(p.pw + (size_t)row*DD);
    q.w[0] = wr[lane]; q.w[1] = wr[lane+64];
    q.b[0] = p.pb[row];
  }
}
__device__ __forceinline__ void issueKV(const P& p, int l, int h, int c, int t,
                                        RegsKV& kv){
  const float* kb = p.k + (size_t)l*SS*DD;
  const float* vb = p.v + (size_t)l*SS*DD;
  const int s0 = c*128;
  kv.k0 = kv.v0 = kv.k1 = kv.v1 = make_float4(0,0,0,0);
  {
    int row = t >> 3, c4 = (t & 7)*4, s = s0 + row;
    if (s < SS){
      kv.k0 = *(const float4*)&kb[(size_t)s*DD + h*32 + c4];
      kv.v0 = *(const float4*)&vb[(size_t)s*DD + h*32 + c4];
    }
  }
  {
    int idx = t + NT;
    int row = idx >> 3, c4 = (idx & 7)*4, s = s0 + row;
    if (s < SS){
      kv.k1 = *(const float4*)&kb[(size_t)s*DD + h*32 + c4];
      kv.v1 = *(const float4*)&vb[(size_t)s*DD + h*32 + c4];
    }
  }
}
__device__ __forceinline__ void issueTl(const P& p, int l, int h, int c, int t,
                                        RegsTl& tl){
  const int lane = t & 63, w = t >> 6;
  if (w < 4){
    int isv = w >> 1;
    int row = 512 + isv*512 + h*32 + c*2 + (w&1);
    const float4* wr = (const float4*)(p.ipw + (size_t)l*1536*DD + (size_t)row*DD);
    tl.t0 = wr[lane]; tl.t1 = wr[lane+64];
    tl.bias = p.ipb[(size_t)l*1536 + row];
  }
}
__device__ __forceinline__ void issueLN(const P& p, int l, int t, RegsLN& r){
  r.g2 = p.l2w[(size_t)l*DD + t];
  r.b2 = p.l2b[(size_t)l*DD + t];
  r.fb2= p.f2b[(size_t)l*DD + t];
}
__device__ __forceinline__ void issueBC(const P& p, int l, int b, int h, int c,
                                        int t, RegsBC& bc){
  const int lane = t & 63, w = t >> 6;
  bc.oww = *(const float2*)(p.ow + (size_t)l*DD*DD
            + (size_t)(c*32 + (t>>4))*DD + h*32 + (t&15)*2);
  {
    int f = b*8 + w;
    const float4* wr = (const float4*)(p.f1w + (size_t)l*FFD*DD + (size_t)f*DD);
    bc.f1p0 = wr[lane]; bc.f1p1 = wr[lane+64];
    bc.f1bv = p.f1b[(size_t)l*FFD + f];
  }
  {
    const float* wr = p.f2w + (size_t)l*DD*FFD + (size_t)t*FFD + b*8;
    bc.f2p0 = *(const float4*)wr;
    bc.f2p1 = *(const float4*)(wr+4);
  }
  bc.g1  = p.l1w[(size_t)l*DD + t];
  bc.b1  = p.l1b[(size_t)l*DD + t];
  bc.obv = p.ob[(size_t)l*DD + t];
}

__global__ __launch_bounds__(NT, 1) void mega_kernel(P p)
{
  __shared__ __align__(16) float S_kl[128*33];   // K tile / sampler overlay
  __shared__ __align__(16) float S_vl[128*33];   // V tile
  __shared__ __align__(16) float S_x[512];
  __shared__ float S_ps[128];
  __shared__ float S_cacc[512];
  __shared__ float S_q[32];
  __shared__ float S_num[32];
  __shared__ float S_kn[32];
  __shared__ float S_vn[32];
  __shared__ float S_ctx[32];
  __shared__ float S_scal[4];
  __shared__ float S_hdn[8];
  __shared__ float2 S_r82[8];
  __shared__ float S_r8v[8];
  __shared__ int   S_r8i[8];

  const int t = threadIdx.x, b = blockIdx.x;
  const int lane = t & 63, w = t >> 6;
  const int h = b & 15, c = b >> 4;
  unsigned* flags = (unsigned*)p.ws;
  float* wsd = p.ws + 4352;
  float* out = p.out;
  unsigned ph = 0;

  RegsQ q; RegsKV kv; RegsTl tl; RegsLN lnp; RegsBC bc;
  issueQ(p, 0, h, t, q);
  issueKV(p, 0, h, c, t, kv);
  issueTl(p, 0, h, c, t, tl);

  for (int l = 0; l < LL; ++l){
    const int par = l & 1, np = (l+1) & 1;
    // ================= PH_A body =================
    float fs = 0.f;
    if (l > 0){
      const float* fb = wsd + W_FFA + (size_t)np*4096;
      #pragma unroll
      for (int i=0;i<8;++i) fs += ldv(&fb[i*512 + t]);
    }
    issueBC(p, l, b, h, c, t, bc);

    if (l == 0){
      int tok = p.y[1535];
      float a0 = p.alpha[0];
      float ev = p.emb[(size_t)tok*DD + t];
      float ang = 1535.0f * expf((float)(2*(t>>1)) * (-9.210340371976184f/512.0f));
      float pe = (t & 1) ? cosf(ang) : sinf(ang);
      S_x[t] = ev + a0*pe;
      if (b == 0) for (int i=t;i<1536;i+=NT)
        __builtin_nontemporal_store((float)p.y[i], out + O_YNEW + i);
      if (b == 1)
        __builtin_nontemporal_store(ev, out + O_YEMB + (size_t)TYY*DD + t);
      lbar();
    } else {
      float r = S_x[t] + lnp.fb2 + fs;
      ln512g(r, lnp.g2, lnp.b2, S_x, S_r82, t);
      lbar();
    }

    // q GEMV
    #pragma unroll
    for (int pp=0; pp<4; ++pp){
      float s = dot4(q.w[2*pp],   ((const float4*)S_x)[lane])
              + dot4(q.w[2*pp+1], ((const float4*)S_x)[lane+64]);
      for (int off=32; off; off>>=1) s += __shfl_xor(s, off);
      if (lane == 0) S_q[w + 8*pp] = s + q.b[pp];
    }
    // tail k/v rows
    if (w < 4){
      int isv = w >> 1;
      int col = h*32 + c*2 + (w & 1);
      float s = dot4(tl.t0, ((const float4*)S_x)[lane])
              + dot4(tl.t1, ((const float4*)S_x)[lane+64]);
      for (int off=32; off; off>>=1) s += __shfl_xor(s, off);
      if (lane == 0){
        float val = s + tl.bias;
        stv(&wsd[(isv ? W_VN : W_KN) + col], val);
        __builtin_nontemporal_store(val,
          out + (isv ? O_VOUT : O_KOUT) + (size_t)l*TKV*DD + (size_t)SS*DD + col);
      }
    }
    // KV regs -> LDS tile
    {
      int r0 = t >> 3, c40 = (t & 7)*4;
      int lb = r0*33 + c40;
      S_kl[lb+0]=kv.k0.x; S_kl[lb+1]=kv.k0.y; S_kl[lb+2]=kv.k0.z; S_kl[lb+3]=kv.k0.w;
      S_vl[lb+0]=kv.v0.x; S_vl[lb+1]=kv.v0.y; S_vl[lb+2]=kv.v0.z; S_vl[lb+3]=kv.v0.w;
      int idx = t + NT;
      int r1 = idx >> 3, c41 = (idx & 7)*4;
      int lb1 = r1*33 + c41;
      S_kl[lb1+0]=kv.k1.x; S_kl[lb1+1]=kv.k1.y; S_kl[lb1+2]=kv.k1.z; S_kl[lb1+3]=kv.k1.w;
      S_vl[lb1+0]=kv.v1.x; S_vl[lb1+1]=kv.v1.y; S_vl[lb1+2]=kv.v1.z; S_vl[lb1+3]=kv.v1.w;
    }
    lbar();

    // scores (max-free, all 512 threads: 4 lanes/row x 8 dims) + PV partial
    {
      const int s0 = c*128;
      {
        int row = t >> 2, d0 = (t & 3) * 8;
        float acc = 0.f;
        #pragma unroll
        for (int j=0;j<8;++j) acc += S_kl[row*33 + d0 + j] * S_q[d0 + j];
        acc += __shfl_xor(acc, 1, 4);
        acc += __shfl_xor(acc, 2, 4);
        if ((t & 3) == 0)
          S_ps[row] = ((s0 + row) < SS) ? expf(acc * 0.17677669529663687f) : 0.f;
      }
      lbar();
      int g = t >> 5, j = t & 31;
      float ca = 0.f;
      #pragma unroll
      for (int i=0;i<8;++i){ int r = g*8+i; ca += S_ps[r]*S_vl[r*33+j]; }
      S_cacc[g*32 + j] = ca;
      lbar();
      if (t < 32){                      // wave0: num[32] -> atomic per-head
        float v2 = 0.f;
        #pragma unroll
        for (int gg=0; gg<16; ++gg) v2 += S_cacc[gg*32 + t];
        atomicAdd(&wsd[W_NUM + par*512 + h*32 + t], v2);
      } else if (t >= 64 && t < 128){   // wave1: den -> atomic per-head
        int ll2 = t - 64;
        float dv = S_ps[ll2] + S_ps[ll2+64];
        for (int off=32; off; off>>=1) dv += __shfl_xor(dv, off);
        if (ll2 == 0) atomicAdd(&wsd[W_DEN + par*256 + h*16], dv);
      }
    }
    barr_arrive(flags, ++ph);
    // ---- post-A window: KV cache copy (nt scalar stores) ----
    {
      const int s0 = c*128;
      float* ko = out + O_KOUT + (size_t)l*TKV*DD;
      float* vo = out + O_VOUT + (size_t)l*TKV*DD;
      {
        int row = t >> 3, c4 = (t & 7)*4, s = s0 + row;
        if (s < SS){
          size_t go = (size_t)s*DD + h*32 + c4;
          __builtin_nontemporal_store(kv.k0.x, ko+go);
          __builtin_nontemporal_store(kv.k0.y, ko+go+1);
          __builtin_nontemporal_store(kv.k0.z, ko+go+2);
          __builtin_nontemporal_store(kv.k0.w, ko+go+3);
          __builtin_nontemporal_store(kv.v0.x, vo+go);
          __builtin_nontemporal_store(kv.v0.y, vo+go+1);
          __builtin_nontemporal_store(kv.v0.z, vo+go+2);
          __builtin_nontemporal_store(kv.v0.w, vo+go+3);
        }
      }
      {
        int idx = t + NT;
        int row = idx >> 3, c4 = (idx & 7)*4, s = s0 + row;
        if (s < SS){
          size_t go = (size_t)s*DD + h*32 + c4;
          __builtin_nontemporal_store(kv.k1.x, ko+go);
          __builtin_nontemporal_store(kv.k1.y, ko+go+1);
          __builtin_nontemporal_store(kv.k1.z, ko+go+2);
          __builtin_nontemporal_store(kv.k1.w, ko+go+3);
          __builtin_nontemporal_store(kv.v1.x, vo+go);
          __builtin_nontemporal_store(kv.v1.y, vo+go+1);
          __builtin_nontemporal_store(kv.v1.z, vo+go+2);
          __builtin_nontemporal_store(kv.v1.w, vo+go+3);
        }
      }
    }
    barr_wait_head(flags, ph, h);      // intra-head: num/den/kn/vn of head h

    // ================= PH_B body =================
    {
      if (t < 32){
        S_num[t] = ldv(&wsd[W_NUM + par*512 + h*32 + t]);
        S_kn[t]  = ldv(&wsd[W_KN + h*32 + t]);
        S_vn[t]  = ldv(&wsd[W_VN + h*32 + t]);
      }
      if (t == 64) S_scal[1] = ldv(&wsd[W_DEN + par*256 + h*16]);
      if (t < 2) stv(&wsd[W_NUM + np*512 + b*2 + t], 0.f);        // zero next parity
      if (b < 16 && t == 96) stv(&wsd[W_DEN + np*256 + b*16], 0.f);
      lbar();
      if (t < 32){
        float tsp = S_q[t] * S_kn[t];
        for (int off=16; off; off>>=1) tsp += __shfl_xor(tsp, off, 32);
        if (t == 0){
          float et = expf(tsp * 0.17677669529663687f);
          S_scal[0] = et;
          S_scal[2] = S_scal[1] + et;
        }
      }
      lbar();
      if (t < 32) S_ctx[t] = (S_num[t] + S_scal[0]*S_vn[t]) / S_scal[2];
      lbar();
      int j2 = (t & 15) * 2;
      float s = bc.oww.x*S_ctx[j2] + bc.oww.y*S_ctx[j2+1];
      s += __shfl_xor(s, 8, 16); s += __shfl_xor(s, 4, 16);
      s += __shfl_xor(s, 2, 16); s += __shfl_xor(s, 1, 16);
      if ((t & 15) == 0)
        atomicAdd(&wsd[W_X1A + par*2048 + (h&3)*512 + c*32 + (t>>4)], s);
    }
    barr_arrive(flags, ++ph);
    // ---- post-B window: next-layer KV tile + tail weights + LN2 params ----
    if (l < 23){
      issueKV(p, l+1, h, c, t, kv);
      issueTl(p, l+1, h, c, t, tl);
    }
    issueLN(p, l, t, lnp);
    barr_wait(flags, ph);              // global (X1A from all heads)

    // ================= PH_C body =================
    {
      float x0 = ldv(&wsd[W_X1A + par*2048       + t]);
      float x1 = ldv(&wsd[W_X1A + par*2048 +  512 + t]);
      float x2 = ldv(&wsd[W_X1A + par*2048 + 1024 + t]);
      float x3 = ldv(&wsd[W_X1A + par*2048 + 1536 + t]);
      float r = S_x[t] + bc.obv + x0 + x1 + x2 + x3;
      ln512g(r, bc.g1, bc.b1, S_x, S_r82, t);
      lbar();
      {
        float s = dot4(bc.f1p0, ((const float4*)S_x)[lane])
                + dot4(bc.f1p1, ((const float4*)S_x)[lane+64]);
        for (int off=32; off; off>>=1) s += __shfl_xor(s, off);
        if (lane == 0) S_hdn[w] = fmaxf(s + bc.f1bv, 0.f);
      }
      lbar();
      float con = bc.f2p0.x*S_hdn[0]+bc.f2p0.y*S_hdn[1]
                + bc.f2p0.z*S_hdn[2]+bc.f2p0.w*S_hdn[3]
                + bc.f2p1.x*S_hdn[4]+bc.f2p1.y*S_hdn[5]
                + bc.f2p1.z*S_hdn[6]+bc.f2p1.w*S_hdn[7];
      atomicAdd(&wsd[W_FFA + (size_t)par*4096 + (size_t)(b&7)*512 + t], con);
      // zero next-parity FFA and X1A
      if (t < 16) stv(&wsd[W_FFA + (size_t)np*4096 + b*16 + t], 0.f);
      if (t < 8)  stv(&wsd[W_X1A + (size_t)np*2048 + b*8 + t], 0.f);
    }
    barr_arrive(flags, ++ph);
    // ---- post-C window: next-layer q weights ----
    if (l < 23) issueQ(p, l+1, h, t, q);
    else        issueL(p, b, t, q);
    barr_wait(flags, ph);              // global (FFA)
  }

  // ================= LOGITS =================
  {
    float fs = 0.f;
    const float* fb = wsd + W_FFA + (size_t)((LL-1)&1)*4096;
    #pragma unroll
    for (int i=0;i<8;++i) fs += ldv(&fb[i*512 + t]);
    float r = S_x[t] + lnp.fb2 + fs;
    ln512g(r, lnp.g2, lnp.b2, S_x, S_r82, t);
    lbar();
    if (w < 4 || (b == 255 && w == 4)){
      int row = (w < 4) ? b*4 + w : 1024;
      float s = dot4(q.w[0], ((const float4*)S_x)[lane])
              + dot4(q.w[1], ((const float4*)S_x)[lane+64]);
      for (int off=32; off; off>>=1) s += __shfl_xor(s, off);
      if (lane == 0) stv(&out[O_LOGITS+row], s + q.b[0]);
    }
  }
  barr_arrive(flags, ++ph);
  barr_wait(flags, ph);

  // ========= SAMPLER (block 0) / yemb copy (blocks 1..255) =========
  if (b == 0){
    float* lg  = S_kl;
    float* lgc = S_kl + 1025;
    int*   pen = (int*)(S_kl + 2050);
    for (int i=t;i<VV;i+=NT){ lg[i] = ldv(&out[O_LOGITS+i]); pen[i]=0; }
    lbar();
    for (int i=t;i<1536;i+=NT) pen[p.y[i]] = 1;
    lbar();
    for (int i=t;i<VV;i+=NT){
      if (pen[i]){ float s = lg[i]; lg[i] = (s<0.f) ? s*1.35f : s/1.35f; }
    }
    lbar();
    for (int i=t;i<VV;i+=NT) lgc[i]=lg[i];
    lbar();
    float sM = 0.f, sPiv = 0.f;
    for (int it=0; it<15; ++it){
      float bv = -INFINITY; int bi = VV;
      for (int i=t;i<VV;i+=NT){ float v2=lgc[i]; if (v2>bv){bv=v2;bi=i;} }
      float ov; int oi;
      bargmax(bv, bi, S_r8v, S_r8i, t, ov, oi);
      if (it==0)  sM   = ov;
      if (it==14) sPiv = ov;
      if (t==0) lgc[oi] = -INFINITY;
      lbar();
    }
    float zl = 0.f;
    for (int i=t;i<VV;i+=NT){
      float lv = lg[i];
      float pv2 = (lv < sPiv) ? 0.f : expf(lv - sM);
      lgc[i] = pv2; zl += pv2;
    }
    {
      float2 s = bsum2(zl, 0.f, S_r82, t);
      zl = s.x;
    }
    lbar();
    float bv=-INFINITY; int bi=VV;
    for (int i=t;i<VV;i+=NT){
      float val = (lgc[i]/zl)/p.noise[i];
      if (val>bv){bv=val;bi=i;}
    }
    float ov; int oi;
    bargmax(bv, bi, S_r8v, S_r8i, t, ov, oi);
    if (t==0){
      float sf = (float)oi;
      out[O_SAMP] = sf;
      out[O_YNEW+1536] = sf;
    }
  } else {
    const int nf4 = (TYY*DD)/4;    // 196608
    for (int qq = (b-1)*NT + t; qq < nf4; qq += 255*NT){
      float4 vq = *(const float4*)&p.yemb[qq*4];
      float* dq = out + O_YEMB + (size_t)qq*4;
      __builtin_nontemporal_store(vq.x, dq);
      __builtin_nontemporal_store(vq.y, dq+1);
      __builtin_nontemporal_store(vq.z, dq+2);
      __builtin_nontemporal_store(vq.w, dq+3);
    }
  }
}

extern "C" void kernel_launch(void* const* d_in, const int* in_sizes, int n_in,
                              void* d_out, int out_size, void* d_ws, size_t ws_size,
                              hipStream_t stream)
{
  P p;
  p.y    = (const int*)d_in[0];
  p.k    = (const float*)d_in[1];
  p.v    = (const float*)d_in[2];
  p.yemb = (const float*)d_in[3];
  p.alpha= (const float*)d_in[5];
  p.emb  = (const float*)d_in[6];
  p.ipw  = (const float*)d_in[7];
  p.ipb  = (const float*)d_in[8];
  p.ow   = (const float*)d_in[9];
  p.ob   = (const float*)d_in[10];
  p.l1w  = (const float*)d_in[11];
  p.l1b  = (const float*)d_in[12];
  p.l2w  = (const float*)d_in[13];
  p.l2b  = (const float*)d_in[14];
  p.f1w  = (const float*)d_in[15];
  p.f1b  = (const float*)d_in[16];
  p.f2w  = (const float*)d_in[17];
  p.f2b  = (const float*)d_in[18];
  p.pw   = (const float*)d_in[19];
  p.pb   = (const float*)d_in[20];
  p.noise= (const float*)d_in[21];
  p.out  = (float*)d_out;
  p.ws   = (float*)d_ws;

  // zero flags (17408 B) + X1A/FFA/NUM/DEN/KN/VN ((4352+14848)*4 = 76800 B)
  hipMemsetAsync(d_ws, 0, 76800, stream);
  void* args[] = { &p };
  hipLaunchCooperativeKernel((void*)mega_kernel, dim3(NBLK), dim3(NT), args, 0, stream);
}